// Round 4
// baseline (2986.432 us; speedup 1.0000x reference)
//
#include <hip/hip_runtime.h>

#define H  64
#define G4 256   // 4*H

typedef float vf4 __attribute__((ext_vector_type(4)));
typedef float vf2 __attribute__((ext_vector_type(2)));

// fast sigmoid/tanh: v_exp_f32 + v_rcp_f32. Safe at +-inf:
//   x->-inf: exp(-x)=inf -> rcp(inf)=0 ; x->+inf: exp(-x)=0 -> rcp(1)=1
__device__ __forceinline__ float sigm(float x) {
    return __builtin_amdgcn_rcpf(1.0f + __expf(-x));
}
__device__ __forceinline__ float tanh_s(float x) {
    return fmaf(2.0f, sigm(2.0f * x), -1.0f);
}
__device__ __forceinline__ float bcast(float v, int lane) {
    return __int_as_float(__builtin_amdgcn_readlane(__float_as_int(v), lane));
}

// P2[v][e][g] = sum_h table[v][h] * w_ih[g*64+e][h] + b_ih + b_hh, table[0]=0.
// Layout [V][64][4] so the lstm consumer reads its 4 gate inputs as 1 dwordx4.
__global__ __launch_bounds__(256)
void proj_kernel(const float* __restrict__ emb,
                 const float* __restrict__ w_ih,
                 const float* __restrict__ b_ih,
                 const float* __restrict__ b_hh,
                 float* __restrict__ P,
                 int V)
{
    const int j  = threadIdx.x;       // gate row 0..255 (g = j>>6, e = j&63)
    const int v0 = blockIdx.x * 8;

    __shared__ float es[8][H];
    {
        int idx = j;
        #pragma unroll
        for (int rep = 0; rep < 2; ++rep, idx += 256) {
            int r = idx >> 6, col = idx & 63;
            int v = v0 + r;
            float val = 0.0f;
            if (v < V && v != 0) val = emb[v * H + col];   // padding_idx=0
            es[r][col] = val;
        }
    }

    vf4 w[16];
    const vf4* w4 = reinterpret_cast<const vf4*>(w_ih + j * H);
    #pragma unroll
    for (int i = 0; i < 16; ++i) w[i] = w4[i];

    float bias = b_ih[j] + b_hh[j];
    __syncthreads();

    const int slot = (j & 63) * 4 + (j >> 6);   // [e][g] position within row
    #pragma unroll
    for (int r = 0; r < 8; ++r) {
        int v = v0 + r;
        if (v >= V) break;
        float a0 = 0, a1 = 0, a2 = 0, a3 = 0;
        #pragma unroll
        for (int i = 0; i < 16; ++i) {
            a0 = fmaf(es[r][4*i+0], w[i][0], a0);
            a1 = fmaf(es[r][4*i+1], w[i][1], a1);
            a2 = fmaf(es[r][4*i+2], w[i][2], a2);
            a3 = fmaf(es[r][4*i+3], w[i][3], a3);
        }
        P[v * G4 + slot] = bias + ((a0 + a1) + (a2 + a3));
    }
}

// ONE WAVE PER BATCH ELEMENT — no cross-wave exchange, no barrier in the
// recurrent loop. Lane l owns all 4 gate rows {l, 64+l, 128+l, 192+l}; h
// stays lane-local (lane l holds h[l]); broadcasts are in-wave readlane
// pairs feeding v_pk_fma_f32 (2 MACs/instr, full-rate packed fp32 on
// gfx950 — the 157.3 TF fp32 peak requires it). i/f/g gate weights live
// in VGPRs (192); o-gate weights live in LDS (per-lane private column,
// volatile ds_read_b64 so they are NOT hoisted back into registers).
// This removes the ~300-400cy LDS-write/barrier/read gate exchange that
// capped every multi-wave variant (R0-R3) at ~1110 cyc/step.
__global__ __launch_bounds__(64, 1)
void lstm_kernel(const int* __restrict__ x,        // [B,T]
                 const float* __restrict__ P2,     // [V][64][4]
                 const float* __restrict__ w_hh,   // [4H,H] (forward)
                 const float* __restrict__ w_ih_b, // [4H,H]
                 const float* __restrict__ b_ih_b, // [4H]
                 const float* __restrict__ b_hh_b, // [4H]
                 const float* __restrict__ emb,    // [V,H]
                 const float* __restrict__ w_fc,   // [12,2H]
                 const float* __restrict__ b_fc,   // [12]
                 float* __restrict__ out,          // [B,12]
                 int T)
{
    const int b    = blockIdx.x;
    const int lane = threadIdx.x;    // 0..63

    __shared__ vf2  wo_s[32][64];    // o-gate weights, [k-pair][lane], 16KB
    __shared__ float hf_s[H];
    __shared__ float hb_s[H];

    // weight rows: gate G row for this lane = w_hh[(G*64 + lane)][:]
    const vf2* ri = reinterpret_cast<const vf2*>(w_hh + (0*64 + lane) * H);
    const vf2* rf = reinterpret_cast<const vf2*>(w_hh + (1*64 + lane) * H);
    const vf2* rg = reinterpret_cast<const vf2*>(w_hh + (2*64 + lane) * H);
    const vf2* ro = reinterpret_cast<const vf2*>(w_hh + (3*64 + lane) * H);
    vf2 wi[32], wf[32], wg[32];
    #pragma unroll
    for (int k = 0; k < 32; ++k) {
        wi[k] = ri[k]; wf[k] = rf[k]; wg[k] = rg[k];
        wo_s[k][lane] = ro[k];
    }
    // no barrier needed: each lane reads back only its own wo_s column.

    const int* __restrict__ xrow = x + (long)b * T;
    const float* __restrict__ Pme = P2 + lane * 4;

    float h = 0.0f;   // lane l holds h[l]
    float c = 0.0f;

    int tok_next = (T > 1) ? xrow[1] : 0;
    vf4 p_cur = *reinterpret_cast<const vf4*>(Pme + (size_t)xrow[0] * G4);

    for (int t = 0; t < T; ++t) {
        // prefetch next timestep's 4 gate inputs (one dwordx4, L2-resident)
        vf4 p_next = *reinterpret_cast<const vf4*>(Pme + (size_t)tok_next * G4);
        int tok_next2 = (t + 2 < T) ? xrow[t + 2] : 0;

        vf2 ai = {0.0f, 0.0f}, af = {0.0f, 0.0f};
        vf2 ag = {0.0f, 0.0f}, ao = {0.0f, 0.0f};
        #pragma unroll
        for (int k = 0; k < 32; ++k) {
            vf2 h2;
            h2.x = bcast(h, 2*k);      // uniform -> SGPR pair for pk_fma
            h2.y = bcast(h, 2*k + 1);
            vf2 wo = *(volatile vf2*)&wo_s[k][lane];   // ds_read_b64, not hoistable
            asm("v_pk_fma_f32 %0, %1, %2, %0" : "+v"(ai) : "v"(wi[k]), "s"(h2));
            asm("v_pk_fma_f32 %0, %1, %2, %0" : "+v"(af) : "v"(wf[k]), "s"(h2));
            asm("v_pk_fma_f32 %0, %1, %2, %0" : "+v"(ag) : "v"(wg[k]), "s"(h2));
            asm("v_pk_fma_f32 %0, %1, %2, %0" : "+v"(ao) : "v"(wo),    "s"(h2));
        }
        float si = (ai.x + ai.y) + p_cur[0];
        float sf = (af.x + af.y) + p_cur[1];
        float sg = (ag.x + ag.y) + p_cur[2];
        float so = (ao.x + ao.y) + p_cur[3];

        float i_ = sigm(si);
        float f_ = sigm(sf);
        float g_ = tanh_s(sg);
        float o_ = sigm(so);
        c = fmaf(f_, c, i_ * g_);
        h = o_ * tanh_s(c);

        p_cur    = p_next;
        tok_next = tok_next2;
    }

    // ---- epilogue ----
    // backward LSTM = exactly one step (hs_b[0]) with zero initial state:
    // gates = w_ih_b . emb[last_token] + biases (f-gate irrelevant, c0=0).
    int tokL = xrow[T - 1];
    float ev = (tokL != 0) ? emb[(size_t)tokL * H + lane] : 0.0f;  // padding_idx=0
    const vf2* bi = reinterpret_cast<const vf2*>(w_ih_b + (0*64 + lane) * H);
    const vf2* bg = reinterpret_cast<const vf2*>(w_ih_b + (2*64 + lane) * H);
    const vf2* bo = reinterpret_cast<const vf2*>(w_ih_b + (3*64 + lane) * H);
    float aI = 0.0f, aG = 0.0f, aO = 0.0f;
    #pragma unroll
    for (int k = 0; k < 32; ++k) {
        float e0 = bcast(ev, 2*k);
        float e1 = bcast(ev, 2*k + 1);
        vf2 vI = bi[k], vG = bg[k], vO = bo[k];
        aI = fmaf(vI.x, e0, aI); aI = fmaf(vI.y, e1, aI);
        aG = fmaf(vG.x, e0, aG); aG = fmaf(vG.y, e1, aG);
        aO = fmaf(vO.x, e0, aO); aO = fmaf(vO.y, e1, aO);
    }
    float ib = sigm(aI + b_ih_b[lane]         + b_hh_b[lane]);
    float gb = tanh_s(aG + b_ih_b[128 + lane] + b_hh_b[128 + lane]);
    float ob = sigm(aO + b_ih_b[192 + lane]   + b_hh_b[192 + lane]);
    float hb = ob * tanh_s(ib * gb);          // f*c0 = 0

    hf_s[lane] = h;
    hb_s[lane] = hb;
    __syncthreads();

    // final FC: y[b, j] = b_fc[j] + [h_f | h_b] . w_fc[j]
    if (lane < 12) {
        float acc = b_fc[lane];
        const float* wfc = w_fc + lane * (2 * H);
        #pragma unroll
        for (int k = 0; k < H; ++k) acc = fmaf(hf_s[k], wfc[k], acc);
        #pragma unroll
        for (int k = 0; k < H; ++k) acc = fmaf(hb_s[k], wfc[H + k], acc);
        out[b * 12 + lane] = acc;
    }
}

extern "C" void kernel_launch(void* const* d_in, const int* in_sizes, int n_in,
                              void* d_out, int out_size, void* d_ws, size_t ws_size,
                              hipStream_t stream)
{
    const int*   x      = (const int*)  d_in[0];
    const float* emb    = (const float*)d_in[1];
    const float* w_ih_f = (const float*)d_in[2];
    const float* w_hh_f = (const float*)d_in[3];
    const float* b_ih_f = (const float*)d_in[4];
    const float* b_hh_f = (const float*)d_in[5];
    const float* w_ih_b = (const float*)d_in[6];
    // d_in[7] = w_hh_b (unused: backward runs exactly one step from zero state)
    const float* b_ih_b = (const float*)d_in[8];
    const float* b_hh_b = (const float*)d_in[9];
    const float* w_fc   = (const float*)d_in[10];
    const float* b_fc   = (const float*)d_in[11];
    float* out = (float*)d_out;

    const int B = out_size / 12;
    const int T = in_sizes[0] / B;
    const int V = in_sizes[1] / H;

    float* Pf = (float*)d_ws;                   // [V][64][4] (2 MB)

    int pblocks = (V + 7) / 8;
    proj_kernel<<<pblocks, 256, 0, stream>>>(emb, w_ih_f, b_ih_f, b_hh_f, Pf, V);
    lstm_kernel<<<B, 64, 0, stream>>>(x, Pf, w_hh_f, w_ih_b, b_ih_b, b_hh_b,
                                      emb, w_fc, b_fc, out, T);
}

// Round 5
// 1439.426 us; speedup vs baseline: 2.0747x; 2.0747x over previous
//
#include <hip/hip_runtime.h>

#define H  64
#define G4 256   // 4*H

typedef float vf4 __attribute__((ext_vector_type(4)));
typedef float vf2 __attribute__((ext_vector_type(2)));

// fast sigmoid/tanh: v_exp_f32 + v_rcp_f32. Safe at +-inf:
//   x->-inf: exp(-x)=inf -> rcp(inf)=0 ; x->+inf: exp(-x)=0 -> rcp(1)=1
__device__ __forceinline__ float sigm(float x) {
    return __builtin_amdgcn_rcpf(1.0f + __expf(-x));
}
__device__ __forceinline__ float tanh_s(float x) {
    return fmaf(2.0f, sigm(2.0f * x), -1.0f);
}
__device__ __forceinline__ float bcast(float v, int lane) {
    return __int_as_float(__builtin_amdgcn_readlane(__float_as_int(v), lane));
}

// P2[v][e][g] = sum_h table[v][h] * w_ih[g*64+e][h] + b_ih + b_hh, table[0]=0.
// Layout [V][64][4] so the lstm consumer reads its 4 gate inputs as 1 dwordx4.
__global__ __launch_bounds__(256)
void proj_kernel(const float* __restrict__ emb,
                 const float* __restrict__ w_ih,
                 const float* __restrict__ b_ih,
                 const float* __restrict__ b_hh,
                 float* __restrict__ P,
                 int V)
{
    const int j  = threadIdx.x;       // gate row 0..255 (g = j>>6, e = j&63)
    const int v0 = blockIdx.x * 8;

    __shared__ float es[8][H];
    {
        int idx = j;
        #pragma unroll
        for (int rep = 0; rep < 2; ++rep, idx += 256) {
            int r = idx >> 6, col = idx & 63;
            int v = v0 + r;
            float val = 0.0f;
            if (v < V && v != 0) val = emb[v * H + col];   // padding_idx=0
            es[r][col] = val;
        }
    }

    vf4 w[16];
    const vf4* w4 = reinterpret_cast<const vf4*>(w_ih + j * H);
    #pragma unroll
    for (int i = 0; i < 16; ++i) w[i] = w4[i];

    float bias = b_ih[j] + b_hh[j];
    __syncthreads();

    const int slot = (j & 63) * 4 + (j >> 6);   // [e][g] position within row
    #pragma unroll
    for (int r = 0; r < 8; ++r) {
        int v = v0 + r;
        if (v >= V) break;
        float a0 = 0, a1 = 0, a2 = 0, a3 = 0;
        #pragma unroll
        for (int i = 0; i < 16; ++i) {
            a0 = fmaf(es[r][4*i+0], w[i][0], a0);
            a1 = fmaf(es[r][4*i+1], w[i][1], a1);
            a2 = fmaf(es[r][4*i+2], w[i][2], a2);
            a3 = fmaf(es[r][4*i+3], w[i][3], a3);
        }
        P[v * G4 + slot] = bias + ((a0 + a1) + (a2 + a3));
    }
}

// ONE WAVE PER BATCH ELEMENT — no cross-wave exchange, no barrier, and NO
// MEMORY AT ALL in the recurrent loop body (except the 1-step-ahead P
// prefetch). Lane l owns all 4 gate rows {l, 64+l, 128+l, 192+l}; h stays
// lane-local; broadcasts are v_readlane pairs feeding v_pk_fma_f32
// (2 MACs/instr). i/f/g weights: 192 arch VGPRs. o weights: 64 AGPRs
// (explicit class-tie asm), read back per-use with v_accvgpr_read — a
// full-rate 2cy VALU op with no wait states. R4's mistake was `volatile`
// LDS loads for o: 32 serialized ds_read round trips = ~3200cy stall/step
// (VALUBusy 7.9% = pure latency). AGPR copies have zero latency exposure.
__global__ __launch_bounds__(64, 1)
void lstm_kernel(const int* __restrict__ x,        // [B,T]
                 const float* __restrict__ P2,     // [V][64][4]
                 const float* __restrict__ w_hh,   // [4H,H] (forward)
                 const float* __restrict__ w_ih_b, // [4H,H]
                 const float* __restrict__ b_ih_b, // [4H]
                 const float* __restrict__ b_hh_b, // [4H]
                 const float* __restrict__ emb,    // [V,H]
                 const float* __restrict__ w_fc,   // [12,2H]
                 const float* __restrict__ b_fc,   // [12]
                 float* __restrict__ out,          // [B,12]
                 int T)
{
    const int b    = blockIdx.x;
    const int lane = threadIdx.x;    // 0..63

    __shared__ float hf_s[H];
    __shared__ float hb_s[H];

    // weight rows: gate G row for this lane = w_hh[(G*64 + lane)][:]
    const vf2* ri = reinterpret_cast<const vf2*>(w_hh + (0*64 + lane) * H);
    const vf2* rf = reinterpret_cast<const vf2*>(w_hh + (1*64 + lane) * H);
    const vf2* rg = reinterpret_cast<const vf2*>(w_hh + (2*64 + lane) * H);
    const vf2* ro = reinterpret_cast<const vf2*>(w_hh + (3*64 + lane) * H);
    vf2 wi[32], wf[32], wg[32];
    vf2 wo_a[32];                    // lives in AGPRs (class-tied below)
    #pragma unroll
    for (int k = 0; k < 32; ++k) {
        wi[k] = ri[k]; wf[k] = rf[k]; wg[k] = rg[k];
        vf2 t = ro[k];
        // force t into the AGPR file: tied-copy through an opaque asm
        asm volatile("" : "=a"(wo_a[k]) : "0"(t));
    }

    const int* __restrict__ xrow = x + (long)b * T;
    const float* __restrict__ Pme = P2 + lane * 4;

    float h = 0.0f;   // lane l holds h[l]
    float c = 0.0f;

    int tok_next = (T > 1) ? xrow[1] : 0;
    vf4 p_cur = *reinterpret_cast<const vf4*>(Pme + (size_t)xrow[0] * G4);

    for (int t = 0; t < T; ++t) {
        // prefetch next timestep's 4 gate inputs (one dwordx4, L2-resident)
        vf4 p_next = *reinterpret_cast<const vf4*>(Pme + (size_t)tok_next * G4);
        int tok_next2 = (t + 2 < T) ? xrow[t + 2] : 0;

        vf2 ai = {0.0f, 0.0f}, af = {0.0f, 0.0f};
        vf2 ag = {0.0f, 0.0f}, ao = {0.0f, 0.0f};
        #pragma unroll
        for (int k = 0; k < 32; ++k) {
            vf2 h2;
            h2.x = bcast(h, 2*k);      // uniform -> SGPR pair for pk_fma
            h2.y = bcast(h, 2*k + 1);
            vf2 wo;
            // AGPR -> VGPR copy (v_accvgpr_read x2). volatile asm: cannot be
            // hoisted (would need 64 VGPRs) yet imposes no memory ordering.
            asm volatile("" : "=v"(wo) : "0"(wo_a[k]));
            asm("v_pk_fma_f32 %0, %1, %2, %0" : "+v"(ai) : "v"(wi[k]), "s"(h2));
            asm("v_pk_fma_f32 %0, %1, %2, %0" : "+v"(af) : "v"(wf[k]), "s"(h2));
            asm("v_pk_fma_f32 %0, %1, %2, %0" : "+v"(ag) : "v"(wg[k]), "s"(h2));
            asm("v_pk_fma_f32 %0, %1, %2, %0" : "+v"(ao) : "v"(wo),    "s"(h2));
        }
        float si = (ai.x + ai.y) + p_cur[0];
        float sf = (af.x + af.y) + p_cur[1];
        float sg = (ag.x + ag.y) + p_cur[2];
        float so = (ao.x + ao.y) + p_cur[3];

        float i_ = sigm(si);
        float f_ = sigm(sf);
        float g_ = tanh_s(sg);
        float o_ = sigm(so);
        c = fmaf(f_, c, i_ * g_);
        h = o_ * tanh_s(c);

        p_cur    = p_next;
        tok_next = tok_next2;
    }

    // ---- epilogue ----
    // backward LSTM = exactly one step (hs_b[0]) with zero initial state:
    // gates = w_ih_b . emb[last_token] + biases (f-gate irrelevant, c0=0).
    int tokL = xrow[T - 1];
    float ev = (tokL != 0) ? emb[(size_t)tokL * H + lane] : 0.0f;  // padding_idx=0
    const vf2* bi = reinterpret_cast<const vf2*>(w_ih_b + (0*64 + lane) * H);
    const vf2* bg = reinterpret_cast<const vf2*>(w_ih_b + (2*64 + lane) * H);
    const vf2* bo = reinterpret_cast<const vf2*>(w_ih_b + (3*64 + lane) * H);
    float aI = 0.0f, aG = 0.0f, aO = 0.0f;
    #pragma unroll
    for (int k = 0; k < 32; ++k) {
        float e0 = bcast(ev, 2*k);
        float e1 = bcast(ev, 2*k + 1);
        vf2 vI = bi[k], vG = bg[k], vO = bo[k];
        aI = fmaf(vI.x, e0, aI); aI = fmaf(vI.y, e1, aI);
        aG = fmaf(vG.x, e0, aG); aG = fmaf(vG.y, e1, aG);
        aO = fmaf(vO.x, e0, aO); aO = fmaf(vO.y, e1, aO);
    }
    float ib = sigm(aI + b_ih_b[lane]         + b_hh_b[lane]);
    float gb = tanh_s(aG + b_ih_b[128 + lane] + b_hh_b[128 + lane]);
    float ob = sigm(aO + b_ih_b[192 + lane]   + b_hh_b[192 + lane]);
    float hb = ob * tanh_s(ib * gb);          // f*c0 = 0

    hf_s[lane] = h;
    hb_s[lane] = hb;
    __syncthreads();

    // final FC: y[b, j] = b_fc[j] + [h_f | h_b] . w_fc[j]
    if (lane < 12) {
        float acc = b_fc[lane];
        const float* wfc = w_fc + lane * (2 * H);
        #pragma unroll
        for (int k = 0; k < H; ++k) acc = fmaf(hf_s[k], wfc[k], acc);
        #pragma unroll
        for (int k = 0; k < H; ++k) acc = fmaf(hb_s[k], wfc[H + k], acc);
        out[b * 12 + lane] = acc;
    }
}

extern "C" void kernel_launch(void* const* d_in, const int* in_sizes, int n_in,
                              void* d_out, int out_size, void* d_ws, size_t ws_size,
                              hipStream_t stream)
{
    const int*   x      = (const int*)  d_in[0];
    const float* emb    = (const float*)d_in[1];
    const float* w_ih_f = (const float*)d_in[2];
    const float* w_hh_f = (const float*)d_in[3];
    const float* b_ih_f = (const float*)d_in[4];
    const float* b_hh_f = (const float*)d_in[5];
    const float* w_ih_b = (const float*)d_in[6];
    // d_in[7] = w_hh_b (unused: backward runs exactly one step from zero state)
    const float* b_ih_b = (const float*)d_in[8];
    const float* b_hh_b = (const float*)d_in[9];
    const float* w_fc   = (const float*)d_in[10];
    const float* b_fc   = (const float*)d_in[11];
    float* out = (float*)d_out;

    const int B = out_size / 12;
    const int T = in_sizes[0] / B;
    const int V = in_sizes[1] / H;

    float* Pf = (float*)d_ws;                   // [V][64][4] (2 MB)

    int pblocks = (V + 7) / 8;
    proj_kernel<<<pblocks, 256, 0, stream>>>(emb, w_ih_f, b_ih_f, b_hh_f, Pf, V);
    lstm_kernel<<<B, 64, 0, stream>>>(x, Pf, w_hh_f, w_ih_b, b_ih_b, b_hh_b,
                                      emb, w_fc, b_fc, out, T);
}